// Round 4
// baseline (1532.707 us; speedup 1.0000x reference)
//
#include <hip/hip_runtime.h>
#include <math.h>

// ---------------------------------------------------------------------------
// CoLT5 MoE layer, round 4: 256x256 8-wave counted-vmcnt MFMA engine (T3+T4+T5)
// with conflict-free k-slot-major LDS layout (16B-permuted staging sources).
//  - router GEMM1 = main (xh*Wh, K=1024) + correction ([xh|xl]*[Wl|Wh], K=2048)
//  - experts: gather-GEMM (token list) -> gelu -> scatter-GEMM (K-split x4,
//    atomicAdd gated epilogue), top-2 sparse
// Shapes hard-coded: T=8192, D=1024, D2=2048, H=4096, E=4.  ws ~121 MB.
// ---------------------------------------------------------------------------

typedef short bf16x8 __attribute__((ext_vector_type(8)));
typedef float f32x4 __attribute__((ext_vector_type(4)));
typedef unsigned short u16;

__device__ __forceinline__ u16 f2bf(float f) {
  unsigned u = __float_as_uint(f);
  u += 0x7FFFu + ((u >> 16) & 1u);  // round-to-nearest-even
  return (u16)(u >> 16);
}
__device__ __forceinline__ float bf2f(u16 s) {
  return __uint_as_float(((unsigned)s) << 16);
}
__device__ __forceinline__ float gelu_f(float x) {
  return 0.5f * x * (1.0f + erff(x * 0.70710678118654752f));
}
__device__ __forceinline__ void gload_lds16(const void* g, void* l) {
  __builtin_amdgcn_global_load_lds(
      (const __attribute__((address_space(1))) void*)g,
      (__attribute__((address_space(3))) void*)l, 16, 0, 0);
}

// ---------------------------------------------------------------------------
// x (fp32 [T][1024]) -> x_cat (bf16 [T][2048] = [hi | lo residual])
// ---------------------------------------------------------------------------
__global__ __launch_bounds__(256) void convert_cat_kernel(
    const float* __restrict__ in, u16* __restrict__ xcat, int n4) {
  int i = blockIdx.x * blockDim.x + threadIdx.x;
  int stride = gridDim.x * blockDim.x;
  for (; i < n4; i += stride) {
    int t = i >> 8;       // 256 float4 per 1024-elem row
    int c4 = i & 255;
    float4 v = ((const float4*)in)[i];
    float f[4] = {v.x, v.y, v.z, v.w};
    ushort4 h4, l4;
    u16* hp = (u16*)&h4;
    u16* lp = (u16*)&l4;
#pragma unroll
    for (int u = 0; u < 4; ++u) {
      u16 h = f2bf(f[u]);
      hp[u] = h;
      lp[u] = f2bf(f[u] - bf2f(h));
    }
    ((ushort4*)(xcat + (size_t)t * 2048))[c4] = h4;
    ((ushort4*)(xcat + (size_t)t * 2048 + 1024))[c4] = l4;
  }
}

// ---------------------------------------------------------------------------
// transpose fp32 [R][C] -> bf16 [C][ostride] (hi at +hi_off, optional lo)
// block (32,8); grid (C/32, R/32)
// ---------------------------------------------------------------------------
__global__ __launch_bounds__(256) void transpose_split_kernel(
    const float* __restrict__ in, u16* __restrict__ hi, u16* __restrict__ lo,
    int R, int C, int ostride) {
  __shared__ float tile[32][33];
  const int c0 = blockIdx.x * 32, r0 = blockIdx.y * 32;
#pragma unroll
  for (int i = 0; i < 4; ++i) {
    int rr = threadIdx.y + i * 8;
    tile[rr][threadIdx.x] = in[(size_t)(r0 + rr) * C + c0 + threadIdx.x];
  }
  __syncthreads();
#pragma unroll
  for (int i = 0; i < 4; ++i) {
    int cc = threadIdx.y + i * 8;
    float v = tile[threadIdx.x][cc];
    u16 h = f2bf(v);
    size_t oidx = (size_t)(c0 + cc) * ostride + r0 + threadIdx.x;
    hi[oidx] = h;
    if (lo) lo[oidx] = f2bf(v - bf2f(h));
  }
}

// ---------------------------------------------------------------------------
// 256x256 GEMM engine: BK=32, 8 waves (2Mx4N, 128x64 per wave), 4-slot LDS
// ring (32 KB/slot = A 16KB + B 16KB, k-slot-major: [ks][row] 16B units ->
// conflict-free ds_read_b128), 2 phases per K-tile, counted vmcnt (8/4/0),
// raw s_barrier, setprio around 16-MFMA clusters.  C = A[M][K] * Bt[N][K]^T.
// EPI: 0 Cf=acc | 1 Cf=gelu(Cf+acc+bias) | 2 Cb=bf16(gelu(acc+bias))
//      3 atomicAdd(out[tok], gate*(acc + bias@z0)), K-split via blockIdx.z
// ---------------------------------------------------------------------------
template <int EPI, bool GATHER>
__global__ __launch_bounds__(512) void gemm256_kernel(
    const u16* __restrict__ A, int lda, int kbaseA,
    const u16* __restrict__ B, int ldb, int kbaseB,
    int K, int N,
    const int* __restrict__ list, const int* __restrict__ cnt_p,
    const float* __restrict__ bias, const float* __restrict__ combine,
    int eidx, float* __restrict__ Cf, u16* __restrict__ Cb, int ldc) {
  int cnt = 0;
  const int rb = blockIdx.y;
  if (GATHER || EPI == 3) {
    cnt = *cnt_p;
    if (rb * 256 >= cnt) return;  // block-uniform early exit
  }
  __shared__ alignas(16) char ldsb[131072];

  const int tid = threadIdx.x;
  const int lane = tid & 63;
  const int w = tid >> 6;
  const int wr = w >> 2, wc = w & 3;
  const int bcol = blockIdx.x * 256;
  const int brow = rb * 256;

  const int kz = (EPI == 3) ? (int)blockIdx.z * K : 0;
  const int kbA = kbaseA + kz, kbB = kbaseB + kz;

  // --- staging geometry: thread -> (r, ks) ; LDS dest = uniform + lane*16 ---
  const int r_st = tid & 255;      // row (A) / col (B) within tile
  const int ks0 = tid >> 8;        // k-slot 0/1 (second unit: +2)
  const int dstA0 = ks0 * 4096 + r_st * 16;
  const int dstA1 = dstA0 + 8192;
  const int dstB0 = dstA0 + 16384;
  const int dstB1 = dstA1 + 16384;

  int arow;
  if (GATHER) {
    int gi = brow + r_st;
    gi = gi < cnt ? gi : cnt - 1;  // clamp (cnt>=1 guaranteed by early exit)
    arow = list[gi];
  } else {
    arow = brow + r_st;
  }
  const u16* aSrc = A + (size_t)arow * lda + kbA;
  const u16* bSrc = B + (size_t)(bcol + r_st) * ldb + kbB;

#define SLOT(kt) (((kt) & 3) * 32768)
#define STAGE_A(kt)                                                   \
  {                                                                   \
    const u16* p_ = aSrc + (size_t)(kt) * 32;                         \
    gload_lds16(p_ + ks0 * 8, ldsb + SLOT(kt) + dstA0);               \
    gload_lds16(p_ + (ks0 + 2) * 8, ldsb + SLOT(kt) + dstA1);         \
  }
#define STAGE_B(kt)                                                   \
  {                                                                   \
    const u16* p_ = bSrc + (size_t)(kt) * 32;                         \
    gload_lds16(p_ + ks0 * 8, ldsb + SLOT(kt) + dstB0);               \
    gload_lds16(p_ + (ks0 + 2) * 8, ldsb + SLOT(kt) + dstB1);         \
  }
#define LDF(off) (*(const bf16x8*)(ldsb + (off)))

  // --- fragment read offsets (k-slot-major: contiguous 256B per 16 lanes) ---
  const int rA = lane & 15;
  const int ksl = lane >> 4;
  const int aOff = ksl * 4096 + (wr * 128 + rA) * 16;           // + m*256
  const int bOff = 16384 + ksl * 4096 + (wc * 64 + rA) * 16;    // + n*256

  const int nkt = K >> 5;  // K-tiles of 32

  // prologue: stage tiles 0,1,2 (12 loads/thread outstanding)
  STAGE_A(0); STAGE_B(0);
  STAGE_A(1); STAGE_B(1);
  STAGE_A(2); STAGE_B(2);

  f32x4 acc[8][4] = {};

  for (int kt = 0; kt < nkt; ++kt) {
    const int sb = SLOT(kt);
    const int rem = nkt - 1 - kt;
    // tile kt's 4 loads are the oldest 4 outstanding
    if (rem >= 2)
      asm volatile("s_waitcnt vmcnt(8)" ::: "memory");
    else if (rem == 1)
      asm volatile("s_waitcnt vmcnt(4)" ::: "memory");
    else
      asm volatile("s_waitcnt vmcnt(0)" ::: "memory");
    __builtin_amdgcn_s_barrier();

    // ---- phase 0: B frags + A frags m0..3, stage A of tile kt+3 ----
    bf16x8 bv[4], av[4];
#pragma unroll
    for (int n = 0; n < 4; ++n) bv[n] = LDF(sb + bOff + n * 256);
#pragma unroll
    for (int m = 0; m < 4; ++m) av[m] = LDF(sb + aOff + m * 256);
    if (kt + 3 < nkt) STAGE_A(kt + 3);
    asm volatile("s_waitcnt lgkmcnt(0)" ::: "memory");
    __builtin_amdgcn_sched_barrier(0);
    __builtin_amdgcn_s_setprio(1);
#pragma unroll
    for (int m = 0; m < 4; ++m)
#pragma unroll
      for (int n = 0; n < 4; ++n)
        acc[m][n] =
            __builtin_amdgcn_mfma_f32_16x16x32_bf16(av[m], bv[n], acc[m][n], 0, 0, 0);
    __builtin_amdgcn_s_setprio(0);
    __builtin_amdgcn_s_barrier();

    // ---- phase 1: A frags m4..7, stage B of tile kt+3 ----
#pragma unroll
    for (int m = 0; m < 4; ++m) av[m] = LDF(sb + aOff + (m + 4) * 256);
    if (kt + 3 < nkt) STAGE_B(kt + 3);
    asm volatile("s_waitcnt lgkmcnt(0)" ::: "memory");
    __builtin_amdgcn_sched_barrier(0);
    __builtin_amdgcn_s_setprio(1);
#pragma unroll
    for (int m = 0; m < 4; ++m)
#pragma unroll
      for (int n = 0; n < 4; ++n)
        acc[m + 4][n] =
            __builtin_amdgcn_mfma_f32_16x16x32_bf16(av[m], bv[n], acc[m + 4][n], 0, 0, 0);
    __builtin_amdgcn_s_setprio(0);
    // next iteration opens with vmcnt-wait + barrier
  }

  // ---- epilogue: C/D layout row=(lane>>4)*4+reg, col=lane&15 ----
  const int cr = (lane >> 4) * 4;
  const int ccx = lane & 15;
#pragma unroll
  for (int m = 0; m < 8; ++m) {
#pragma unroll
    for (int n = 0; n < 4; ++n) {
      const int gc = bcol + wc * 64 + n * 16 + ccx;
#pragma unroll
      for (int r = 0; r < 4; ++r) {
        const int grl = wr * 128 + m * 16 + cr + r;
        if (EPI == 0) {
          Cf[(size_t)(brow + grl) * N + gc] = acc[m][n][r];
        } else if (EPI == 1) {
          const size_t idx = (size_t)(brow + grl) * N + gc;
          Cf[idx] = gelu_f(Cf[idx] + acc[m][n][r] + bias[gc]);
        } else if (EPI == 2) {
          Cb[(size_t)(brow + grl) * ldc + gc] = f2bf(gelu_f(acc[m][n][r] + bias[gc]));
        } else {
          const int gl = brow + grl;
          if (gl < cnt) {
            const int tok = list[gl];
            const float g = combine[(size_t)tok * 4 + eidx];
            float v = acc[m][n][r];
            if (blockIdx.z == 0) v += bias[gc];
            atomicAdd(&Cf[(size_t)tok * N + gc], g * v);
          }
        }
      }
    }
  }
#undef SLOT
#undef STAGE_A
#undef STAGE_B
#undef LDF
}

// ---------------------------------------------------------------------------
// logits = rh[T][2048] @ rW2[2048][4] + rb2.  One wave per token, no atomics.
// ---------------------------------------------------------------------------
__global__ __launch_bounds__(256) void logits_kernel(
    const float* __restrict__ rh, const float* __restrict__ rW2,
    const float* __restrict__ rb2, float* __restrict__ logits, int T) {
  const int w = threadIdx.x >> 6, lane = threadIdx.x & 63;
  const int t = blockIdx.x * 4 + w;
  if (t >= T) return;
  const float4* rp = (const float4*)(rh + (size_t)t * 2048);
  const float4* wp = (const float4*)rW2;
  float s0 = 0.f, s1 = 0.f, s2 = 0.f, s3 = 0.f;
#pragma unroll 4
  for (int j = 0; j < 8; ++j) {
    int idx = j * 64 + lane;
    float4 v = rp[idx];
    float xv[4] = {v.x, v.y, v.z, v.w};
#pragma unroll
    for (int u = 0; u < 4; ++u) {
      float4 wv = wp[idx * 4 + u];
      s0 += xv[u] * wv.x;
      s1 += xv[u] * wv.y;
      s2 += xv[u] * wv.z;
      s3 += xv[u] * wv.w;
    }
  }
#pragma unroll
  for (int off = 32; off; off >>= 1) {
    s0 += __shfl_down(s0, off);
    s1 += __shfl_down(s1, off);
    s2 += __shfl_down(s2, off);
    s3 += __shfl_down(s3, off);
  }
  if (lane == 0) {
    float4 lg = {s0 + rb2[0], s1 + rb2[1], s2 + rb2[2], s3 + rb2[3]};
    ((float4*)logits)[t] = lg;
  }
}

// ---------------------------------------------------------------------------
// topk: softmax + top-2 -> combine[T][4]; per-expert token lists with
// two-level aggregation (wave ballot -> block LDS -> 1 atomic/expert/block).
// ---------------------------------------------------------------------------
__global__ __launch_bounds__(256) void topk_kernel(
    const float* __restrict__ logits, float* __restrict__ combine,
    int* __restrict__ cnt, int* __restrict__ list, int T) {
  const int t = blockIdx.x * 256 + threadIdx.x;
  const int w = threadIdx.x >> 6, lane = threadIdx.x & 63;
  __shared__ int wpre[4][4];
  __shared__ int gbase[4];

  float4 lv = ((const float4*)logits)[t];
  float lg[4] = {lv.x, lv.y, lv.z, lv.w};
  float mx = fmaxf(fmaxf(lg[0], lg[1]), fmaxf(lg[2], lg[3]));
  float p[4], sum = 0.f;
#pragma unroll
  for (int e = 0; e < 4; ++e) {
    p[e] = expf(lg[e] - mx);
    sum += p[e];
  }
  float inv = 1.0f / sum;
  int i1 = 0;
#pragma unroll
  for (int e = 1; e < 4; ++e)
    if (lg[e] > lg[i1]) i1 = e;  // strict > : lowest index wins ties (jax)
  int i2 = -1;
#pragma unroll
  for (int e = 0; e < 4; ++e)
    if (e != i1 && (i2 < 0 || lg[e] > lg[i2])) i2 = e;
  float4 cw = {0.f, 0.f, 0.f, 0.f};
  ((float*)&cw)[i1] = p[i1] * inv;
  ((float*)&cw)[i2] = p[i2] * inv;
  ((float4*)combine)[t] = cw;

  unsigned long long m[4];
#pragma unroll
  for (int e = 0; e < 4; ++e) m[e] = __ballot(i1 == e || i2 == e);
  if (lane == 0) {
#pragma unroll
    for (int e = 0; e < 4; ++e) wpre[w][e] = (int)__popcll(m[e]);
  }
  __syncthreads();
  if (threadIdx.x < 4) {
    const int e = threadIdx.x;
    int tot = 0;
#pragma unroll
    for (int ww = 0; ww < 4; ++ww) {
      int c = wpre[ww][e];
      wpre[ww][e] = tot;
      tot += c;
    }
    gbase[e] = atomicAdd(&cnt[e], tot);
  }
  __syncthreads();
  const unsigned long long lt = (1ull << lane) - 1ull;
  int p1 = gbase[i1] + wpre[w][i1] + (int)__popcll(m[i1] & lt);
  list[i1 * 8192 + p1] = t;
  int p2 = gbase[i2] + wpre[w][i2] + (int)__popcll(m[i2] & lt);
  list[i2 * 8192 + p2] = t;
}

// ---------------------------------------------------------------------------
extern "C" void kernel_launch(void* const* d_in, const int* in_sizes, int n_in,
                              void* d_out, int out_size, void* d_ws,
                              size_t ws_size, hipStream_t stream) {
  const float* x = (const float*)d_in[0];
  const float* rW1 = (const float*)d_in[1];
  const float* rb1 = (const float*)d_in[2];
  const float* rW2 = (const float*)d_in[3];
  const float* rb2 = (const float*)d_in[4];
  const float* We1 = (const float*)d_in[5];
  const float* be1 = (const float*)d_in[6];
  const float* We2 = (const float*)d_in[7];
  const float* be2 = (const float*)d_in[8];
  float* out = (float*)d_out;

  const int T = 8192, D = 1024, D2 = 2048, H = 4096, E = 4;

  char* ws = (char*)d_ws;
  size_t off = 0;
  auto alloc = [&](size_t bytes) {
    char* p = ws + off;
    off = (off + bytes + 255) & ~(size_t)255;
    return p;
  };
  u16* x_cat = (u16*)alloc((size_t)T * 2048 * 2);        // [T][hi|lo] 32 MB
  u16* rW1T_cat = (u16*)alloc((size_t)D2 * 2048 * 2);    // [n][lo|hi]  8 MB
  float* rh = (float*)alloc((size_t)T * D2 * 4);         // 64 MB (h aliases)
  u16* h = (u16*)rh;                                     // [8192][4096] bf16
  float* combine = (float*)alloc((size_t)T * 4 * 4);
  float* logits = (float*)alloc((size_t)T * 4 * 4);
  int* cnt = (int*)alloc(4 * 4);
  int* list = (int*)alloc((size_t)4 * 8192 * 4);
  u16* We1T = (u16*)alloc((size_t)H * D * 2);            // 8 MB
  u16* We2T = (u16*)alloc((size_t)D * H * 2);            // 8 MB
  (void)ws_size;  // ~121 MB required

  hipMemsetAsync(cnt, 0, 16, stream);
  hipMemsetAsync(out, 0, (size_t)T * D * 4, stream);

  dim3 tb(32, 8);

  // 1. x -> x_cat = [hi | lo]
  convert_cat_kernel<<<2048, 256, 0, stream>>>(x, x_cat, T * 256);
  // 2. rW1 [1024][2048] -> rW1T_cat [2048][lo | hi]
  transpose_split_kernel<<<dim3(D2 / 32, D / 32), tb, 0, stream>>>(
      rW1, rW1T_cat + 1024, rW1T_cat, D, D2, 2048);
  // 3. router GEMM1: corr = xh*Wl + xl*Wh (K=2048), then main xh*Wh + gelu
  gemm256_kernel<0, false><<<dim3(D2 / 256, T / 256), 512, 0, stream>>>(
      x_cat, 2048, 0, rW1T_cat, 2048, 0, 2048, D2, nullptr, nullptr, nullptr,
      nullptr, 0, rh, nullptr, 0);
  gemm256_kernel<1, false><<<dim3(D2 / 256, T / 256), 512, 0, stream>>>(
      x_cat, 2048, 0, rW1T_cat, 2048, 1024, 1024, D2, nullptr, nullptr, rb1,
      nullptr, 0, rh, nullptr, 0);
  // 4. router head
  logits_kernel<<<T / 4, 256, 0, stream>>>(rh, rW2, rb2, logits, T);
  topk_kernel<<<T / 256, 256, 0, stream>>>(logits, combine, cnt, list, T);
  // 5. sparse experts: gather-GEMM -> h, scatter-GEMM (K-split x4, atomic +=)
  for (int e = 0; e < E; ++e) {
    transpose_split_kernel<<<dim3(H / 32, D / 32), tb, 0, stream>>>(
        We1 + (size_t)e * D * H, We1T, nullptr, D, H, D);
    gemm256_kernel<2, true><<<dim3(H / 256, T / 256), 512, 0, stream>>>(
        x_cat, 2048, 0, We1T, 1024, 0, 1024, H, list + e * 8192, cnt + e,
        be1 + (size_t)e * H, nullptr, 0, nullptr, h, H);
    transpose_split_kernel<<<dim3(D / 32, H / 32), tb, 0, stream>>>(
        We2 + (size_t)e * H * D, We2T, nullptr, H, D, H);
    gemm256_kernel<3, false><<<dim3(D / 256, T / 256, 4), 512, 0, stream>>>(
        h, 4096, 0, We2T, 4096, 0, 1024, D, list + e * 8192, cnt + e,
        be2 + (size_t)e * D, combine, e, out, nullptr, 0);
  }
}

// Round 5
// 1093.934 us; speedup vs baseline: 1.4011x; 1.4011x over previous
//
#include <hip/hip_runtime.h>
#include <math.h>

// ---------------------------------------------------------------------------
// CoLT5 MoE layer, round 5 (base = round 3, 939us; round-4 8-phase reverted):
//  - gemm3 epilogue computes PARTIAL ROUTER LOGITS directly (rh never hits
//    HBM: -70MB write, -67MB read, -1 dispatch)
//  - fused per-expert weight-transpose pair (one dispatch per expert)
//  - chunked bijective XCD swizzle on gemm3/gather/scatter
// Shapes hard-coded: T=8192, D=1024, D2=2048, H=4096, E=4.  ws ~116 MB.
// ---------------------------------------------------------------------------

typedef short bf16x8 __attribute__((ext_vector_type(8)));
typedef float f32x4 __attribute__((ext_vector_type(4)));
typedef unsigned short u16;

__device__ __forceinline__ u16 f2bf(float f) {
  unsigned u = __float_as_uint(f);
  u += 0x7FFFu + ((u >> 16) & 1u);  // round-to-nearest-even
  return (u16)(u >> 16);
}
__device__ __forceinline__ float bf2f(u16 s) {
  return __uint_as_float(((unsigned)s) << 16);
}
__device__ __forceinline__ float gelu_f(float x) {
  return 0.5f * x * (1.0f + erff(x * 0.70710678118654752f));
}
__device__ __forceinline__ void gload_lds16(const void* g, void* l) {
  __builtin_amdgcn_global_load_lds(
      (const __attribute__((address_space(1))) void*)g,
      (__attribute__((address_space(3))) void*)l, 16, 0, 0);
}

// ---------------------------------------------------------------------------
// x (fp32) -> x_hi (bf16) + x_lo (bf16 residual); vectorized 8B stores
// ---------------------------------------------------------------------------
__global__ __launch_bounds__(256) void convert_split_kernel(
    const float* __restrict__ in, u16* __restrict__ hi, u16* __restrict__ lo,
    int n4) {
  int i = blockIdx.x * blockDim.x + threadIdx.x;
  int stride = gridDim.x * blockDim.x;
  for (; i < n4; i += stride) {
    float4 v = ((const float4*)in)[i];
    float f[4] = {v.x, v.y, v.z, v.w};
    ushort4 h4, l4;
    u16* hp = (u16*)&h4;
    u16* lp = (u16*)&l4;
#pragma unroll
    for (int u = 0; u < 4; ++u) {
      u16 h = f2bf(f[u]);
      hp[u] = h;
      lp[u] = f2bf(f[u] - bf2f(h));
    }
    ((ushort4*)hi)[i] = h4;
    ((ushort4*)lo)[i] = l4;
  }
}

// ---------------------------------------------------------------------------
// transpose fp32 [R][C] -> bf16 [C][R] hi + lo residual (for rW1)
// block (32,8); grid (C/32, R/32)
// ---------------------------------------------------------------------------
__global__ __launch_bounds__(256) void transpose_split_kernel(
    const float* __restrict__ in, u16* __restrict__ hi, u16* __restrict__ lo,
    int R, int C) {
  __shared__ float tile[32][33];
  const int c0 = blockIdx.x * 32, r0 = blockIdx.y * 32;
#pragma unroll
  for (int i = 0; i < 4; ++i) {
    int rr = threadIdx.y + i * 8;
    tile[rr][threadIdx.x] = in[(size_t)(r0 + rr) * C + c0 + threadIdx.x];
  }
  __syncthreads();
#pragma unroll
  for (int i = 0; i < 4; ++i) {
    int cc = threadIdx.y + i * 8;
    float v = tile[threadIdx.x][cc];
    u16 h = f2bf(v);
    size_t oidx = (size_t)(c0 + cc) * R + r0 + threadIdx.x;
    hi[oidx] = h;
    lo[oidx] = f2bf(v - bf2f(h));
  }
}

// ---------------------------------------------------------------------------
// fused expert-weight transpose: We1[e] [1024][4096] -> We1T [4096][1024] and
// We2[e] [4096][1024] -> We2T [1024][4096], both fp32->bf16.  grid 8192 flat.
// ---------------------------------------------------------------------------
__global__ __launch_bounds__(256) void transpose_pair_kernel(
    const float* __restrict__ We1e, const float* __restrict__ We2e,
    u16* __restrict__ We1T, u16* __restrict__ We2T) {
  __shared__ float tile[32][33];
  int b = blockIdx.x;
  const float* in;
  u16* out;
  int R, C, tx, ty;
  if (b < 4096) {
    in = We1e; out = We1T; R = 1024; C = 4096; tx = b & 127; ty = b >> 7;
  } else {
    b -= 4096;
    in = We2e; out = We2T; R = 4096; C = 1024; tx = b & 31; ty = b >> 5;
  }
  const int c0 = tx * 32, r0 = ty * 32;
#pragma unroll
  for (int i = 0; i < 4; ++i) {
    int rr = threadIdx.y + i * 8;
    tile[rr][threadIdx.x] = in[(size_t)(r0 + rr) * C + c0 + threadIdx.x];
  }
  __syncthreads();
#pragma unroll
  for (int i = 0; i < 4; ++i) {
    int cc = threadIdx.y + i * 8;
    out[(size_t)(c0 + cc) * R + r0 + threadIdx.x] = f2bf(tile[threadIdx.x][cc]);
  }
}

// ---------------------------------------------------------------------------
// Fused 3-product split-bf16 router GEMM + partial-logits epilogue:
//   z = gelu( x_hi*W_hi + x_lo*W_hi + x_hi*W_lo + rb1 )   (fp32, in-reg only)
//   parts[bx][row][e] = sum_{cols of this block} z * rW2[col][e]
// 128x128 tile, BK=32, 4 waves.  grid (16, 64), chunked XCD swizzle.
// ---------------------------------------------------------------------------
__global__ __launch_bounds__(256) void gemm3_router_kernel(
    const u16* __restrict__ Ahi, const u16* __restrict__ Alo,
    const u16* __restrict__ Bhi, const u16* __restrict__ Blo, int K,
    const float* __restrict__ bias, const float* __restrict__ rW2,
    float* __restrict__ parts) {
  __shared__ alignas(16) u16 Sm[4 * 128 * 32];
  __shared__ float pls[2][128][4];
  const int tid = threadIdx.x;
  const int lane = tid & 63;
  const int w = tid >> 6;
  const int wr = w >> 1, wc = w & 1;

  // chunked bijective XCD swizzle (nwg = 16*64 = 1024, cpx = 128)
  const int flat = blockIdx.x + blockIdx.y * 16;
  const int swz = (flat & 7) * 128 + (flat >> 3);
  const int bxs = swz & 15;
  const int bys = swz >> 4;
  const int brow = bys * 128;
  const int bcol = bxs * 128;

  f32x4 acc[4][4] = {};
  char* S = (char*)Sm;
  const u16* srcs[4] = {Ahi + (size_t)brow * K, Alo + (size_t)brow * K,
                        Bhi + (size_t)bcol * K, Blo + (size_t)bcol * K};
  const int rA = lane & 15;
  const int kg2 = (lane >> 4) * 16;

  const int nk = K >> 5;
  for (int kt = 0; kt < nk; ++kt) {
    const int k0 = kt << 5;
    __syncthreads();
#pragma unroll
    for (int i = 0; i < 8; ++i) {
      int c = tid + 256 * i;
      int tile = c >> 9;
      int cc = c & 511;
      int row = cc >> 2;
      int kp = (cc & 3) << 3;
      gload_lds16(srcs[tile] + (size_t)row * K + (k0 + kp), S + c * 16);
    }
    __syncthreads();

    bf16x8 ah[4], al[4], bh[4], bl[4];
#pragma unroll
    for (int m = 0; m < 4; ++m) {
      int ro = (wr * 64 + m * 16 + rA) * 64 + kg2;
      ah[m] = *(const bf16x8*)(S + ro);
      al[m] = *(const bf16x8*)(S + 8192 + ro);
    }
#pragma unroll
    for (int n = 0; n < 4; ++n) {
      int ro = (wc * 64 + n * 16 + rA) * 64 + kg2;
      bh[n] = *(const bf16x8*)(S + 16384 + ro);
      bl[n] = *(const bf16x8*)(S + 24576 + ro);
    }
#pragma unroll
    for (int m = 0; m < 4; ++m)
#pragma unroll
      for (int n = 0; n < 4; ++n) {
        acc[m][n] = __builtin_amdgcn_mfma_f32_16x16x32_bf16(ah[m], bh[n], acc[m][n], 0, 0, 0);
        acc[m][n] = __builtin_amdgcn_mfma_f32_16x16x32_bf16(al[m], bh[n], acc[m][n], 0, 0, 0);
        acc[m][n] = __builtin_amdgcn_mfma_f32_16x16x32_bf16(ah[m], bl[n], acc[m][n], 0, 0, 0);
      }
  }

  // ---- epilogue: partial logits over this block's 128 cols ----
  // C/D layout: row=(lane>>4)*4+reg, col=lane&15  [measured m89/m91]
  const int cr = (lane >> 4) * 4;
  const int ccx = lane & 15;
  float4 w2v[4];
  float bv[4];
#pragma unroll
  for (int n = 0; n < 4; ++n) {
    const int gc = bcol + wc * 64 + n * 16 + ccx;
    w2v[n] = ((const float4*)rW2)[gc];
    bv[n] = bias[gc];
  }
#pragma unroll
  for (int m = 0; m < 4; ++m) {
    float pl[4][4];
#pragma unroll
    for (int r = 0; r < 4; ++r)
#pragma unroll
      for (int e = 0; e < 4; ++e) pl[r][e] = 0.f;
#pragma unroll
    for (int n = 0; n < 4; ++n)
#pragma unroll
      for (int r = 0; r < 4; ++r) {
        const float v = gelu_f(acc[m][n][r] + bv[n]);
        pl[r][0] += v * w2v[n].x;
        pl[r][1] += v * w2v[n].y;
        pl[r][2] += v * w2v[n].z;
        pl[r][3] += v * w2v[n].w;
      }
    // reduce across the 16 lanes holding this row's cols (lane bits 0..3)
#pragma unroll
    for (int off = 8; off; off >>= 1)
#pragma unroll
      for (int r = 0; r < 4; ++r)
#pragma unroll
        for (int e = 0; e < 4; ++e) pl[r][e] += __shfl_xor(pl[r][e], off);
    if ((lane & 15) == 0) {
      const int row = wr * 64 + m * 16 + cr;
#pragma unroll
      for (int r = 0; r < 4; ++r)
#pragma unroll
        for (int e = 0; e < 4; ++e) pls[wc][row + r][e] = pl[r][e];
    }
  }
  __syncthreads();
  for (int i = tid; i < 512; i += 256) {
    const int row = i >> 2, e = i & 3;
    parts[((size_t)bxs * 8192 + brow + row) * 4 + e] =
        pls[0][row][e] + pls[1][row][e];
  }
}

// ---------------------------------------------------------------------------
// topk: logits = rb2 + sum_{s<16} parts[s][t][:] (fixed order, deterministic);
// softmax + top-2 -> combine[T][4]; per-expert token lists (wave ballot ->
// block LDS -> 1 atomic/expert/block).  One thread per token.
// ---------------------------------------------------------------------------
__global__ __launch_bounds__(256) void topk_kernel(
    const float* __restrict__ parts, const float* __restrict__ rb2,
    float* __restrict__ combine, int* __restrict__ cnt, int* __restrict__ list,
    int T) {
  const int t = blockIdx.x * 256 + threadIdx.x;
  const int w = threadIdx.x >> 6, lane = threadIdx.x & 63;
  __shared__ int wpre[4][4];
  __shared__ int gbase[4];

  float lg[4] = {rb2[0], rb2[1], rb2[2], rb2[3]};
#pragma unroll
  for (int s = 0; s < 16; ++s) {
    float4 pv = ((const float4*)parts)[(size_t)s * 8192 + t];
    lg[0] += pv.x;
    lg[1] += pv.y;
    lg[2] += pv.z;
    lg[3] += pv.w;
  }
  float mx = fmaxf(fmaxf(lg[0], lg[1]), fmaxf(lg[2], lg[3]));
  float p[4], sum = 0.f;
#pragma unroll
  for (int e = 0; e < 4; ++e) {
    p[e] = expf(lg[e] - mx);
    sum += p[e];
  }
  float inv = 1.0f / sum;
  int i1 = 0;
#pragma unroll
  for (int e = 1; e < 4; ++e)
    if (lg[e] > lg[i1]) i1 = e;  // strict > : lowest index wins ties (jax)
  int i2 = -1;
#pragma unroll
  for (int e = 0; e < 4; ++e)
    if (e != i1 && (i2 < 0 || lg[e] > lg[i2])) i2 = e;
  float4 cw = {0.f, 0.f, 0.f, 0.f};
  ((float*)&cw)[i1] = p[i1] * inv;
  ((float*)&cw)[i2] = p[i2] * inv;
  ((float4*)combine)[t] = cw;

  unsigned long long m[4];
#pragma unroll
  for (int e = 0; e < 4; ++e) m[e] = __ballot(i1 == e || i2 == e);
  if (lane == 0) {
#pragma unroll
    for (int e = 0; e < 4; ++e) wpre[w][e] = (int)__popcll(m[e]);
  }
  __syncthreads();
  if (threadIdx.x < 4) {
    const int e = threadIdx.x;
    int tot = 0;
#pragma unroll
    for (int ww = 0; ww < 4; ++ww) {
      int c = wpre[ww][e];
      wpre[ww][e] = tot;
      tot += c;
    }
    gbase[e] = atomicAdd(&cnt[e], tot);
  }
  __syncthreads();
  const unsigned long long lt = (1ull << lane) - 1ull;
  int p1 = gbase[i1] + wpre[w][i1] + (int)__popcll(m[i1] & lt);
  list[i1 * 8192 + p1] = t;
  int p2 = gbase[i2] + wpre[w][i2] + (int)__popcll(m[i2] & lt);
  list[i2 * 8192 + p2] = t;
}

// ---------------------------------------------------------------------------
// gather-GEMM (expert GEMM-A): rows = list[e] tokens of x_hi; Bt = We1T[e];
// h[packed] = bf16(gelu(acc + be1)).  grid (32, 64), swizzled; early-exit.
// ---------------------------------------------------------------------------
__global__ __launch_bounds__(256) void gemm_gather_kernel(
    const u16* __restrict__ A, const u16* __restrict__ Bt,
    const int* __restrict__ list, const int* __restrict__ cnt_p, int K,
    const float* __restrict__ bias, u16* __restrict__ Cb, int N) {
  // chunked bijective XCD swizzle (nwg = 32*64 = 2048, cpx = 256)
  const int flat = blockIdx.x + blockIdx.y * 32;
  const int swz = (flat & 7) * 256 + (flat >> 3);
  const int bxs = swz & 31;
  const int rb = swz >> 5;

  const int cnt = *cnt_p;
  if (rb * 128 >= cnt) return;
  __shared__ alignas(16) u16 As[128 * 32];
  __shared__ alignas(16) u16 Bs[128 * 32];
  const int tid = threadIdx.x;
  const int lane = tid & 63;
  const int w = tid >> 6;
  const int wr = w >> 1, wc = w & 1;
  const int bcol = bxs * 128;

  // indirect A-row sources (per-lane global addresses; LDS dest stays linear)
  const int arow = tid >> 2;
  const int kp = (tid & 3) << 3;
  int g0 = rb * 128 + arow, g1 = g0 + 64;
  const int tok0 = (g0 < cnt) ? list[g0] : list[rb * 128];
  const int tok1 = (g1 < cnt) ? list[g1] : list[rb * 128];
  const u16* Asrc0 = A + (size_t)tok0 * K + kp;
  const u16* Asrc1 = A + (size_t)tok1 * K + kp;
  const u16* Bb = Bt + (size_t)bcol * K + (size_t)arow * K + kp;

  f32x4 acc[4][4] = {};
  char* AsB = (char*)As;
  char* BsB = (char*)Bs;
  const int rA = lane & 15;
  const int kg2 = (lane >> 4) * 16;

  const int nk = K >> 5;
  for (int kt = 0; kt < nk; ++kt) {
    const int k0 = kt << 5;
    __syncthreads();
    gload_lds16(Asrc0 + k0, AsB + tid * 16);
    gload_lds16(Asrc1 + k0, AsB + (tid + 256) * 16);
    gload_lds16(Bb + k0, BsB + tid * 16);
    gload_lds16(Bb + (size_t)64 * K + k0, BsB + (tid + 256) * 16);
    __syncthreads();

    bf16x8 a[4], b[4];
#pragma unroll
    for (int m = 0; m < 4; ++m)
      a[m] = *(const bf16x8*)(AsB + (wr * 64 + m * 16 + rA) * 64 + kg2);
#pragma unroll
    for (int n = 0; n < 4; ++n)
      b[n] = *(const bf16x8*)(BsB + (wc * 64 + n * 16 + rA) * 64 + kg2);
#pragma unroll
    for (int m = 0; m < 4; ++m)
#pragma unroll
      for (int n = 0; n < 4; ++n)
        acc[m][n] = __builtin_amdgcn_mfma_f32_16x16x32_bf16(a[m], b[n], acc[m][n], 0, 0, 0);
  }

  const int cr = (lane >> 4) * 4;
  const int ccx = lane & 15;
#pragma unroll
  for (int m = 0; m < 4; ++m)
#pragma unroll
    for (int n = 0; n < 4; ++n) {
      const int gc = bcol + wc * 64 + n * 16 + ccx;
      const float bv = bias[gc];
#pragma unroll
      for (int r = 0; r < 4; ++r) {
        const int gr = rb * 128 + wr * 64 + m * 16 + cr + r;
        Cb[(size_t)gr * N + gc] = f2bf(gelu_f(acc[m][n][r] + bv));
      }
    }
}

// ---------------------------------------------------------------------------
// scatter-GEMM (expert GEMM-B): A = packed h; out[tok] += g*(acc + be2).
// grid (8, 64), swizzled; early-exit.  Safe +=: one owner per (tok,col),
// experts serialized; out pre-zeroed.
// ---------------------------------------------------------------------------
__global__ __launch_bounds__(256) void gemm_scatter_kernel(
    const u16* __restrict__ A, const u16* __restrict__ Bt,
    const int* __restrict__ list, const int* __restrict__ cnt_p, int K, int e,
    const float* __restrict__ bias, const float* __restrict__ combine,
    float* __restrict__ out, int N) {
  // chunked bijective XCD swizzle (nwg = 8*64 = 512, cpx = 64)
  const int flat = blockIdx.x + blockIdx.y * 8;
  const int swz = (flat & 7) * 64 + (flat >> 3);
  const int bxs = swz & 7;
  const int rb = swz >> 3;

  const int cnt = *cnt_p;
  if (rb * 128 >= cnt) return;
  __shared__ alignas(16) u16 As[128 * 32];
  __shared__ alignas(16) u16 Bs[128 * 32];
  const int tid = threadIdx.x;
  const int lane = tid & 63;
  const int w = tid >> 6;
  const int wr = w >> 1, wc = w & 1;
  const int bcol = bxs * 128;

  const u16* Ab = A + (size_t)rb * 128 * K;
  const u16* Bb = Bt + (size_t)bcol * K;
  f32x4 acc[4][4] = {};
  char* AsB = (char*)As;
  char* BsB = (char*)Bs;
  const int rA = lane & 15;
  const int kg2 = (lane >> 4) * 16;

  const int nk = K >> 5;
  for (int kt = 0; kt < nk; ++kt) {
    const int k0 = kt << 5;
    __syncthreads();
#pragma unroll
    for (int i = 0; i < 2; ++i) {
      int c = tid + 256 * i;
      int row = c >> 2;
      int kpp = (c & 3) << 3;
      gload_lds16(Ab + (size_t)row * K + (k0 + kpp), AsB + c * 16);
      gload_lds16(Bb + (size_t)row * K + (k0 + kpp), BsB + c * 16);
    }
    __syncthreads();

    bf16x8 a[4], b[4];
#pragma unroll
    for (int m = 0; m < 4; ++m)
      a[m] = *(const bf16x8*)(AsB + (wr * 64 + m * 16 + rA) * 64 + kg2);
#pragma unroll
    for (int n = 0; n < 4; ++n)
      b[n] = *(const bf16x8*)(BsB + (wc * 64 + n * 16 + rA) * 64 + kg2);
#pragma unroll
    for (int m = 0; m < 4; ++m)
#pragma unroll
      for (int n = 0; n < 4; ++n)
        acc[m][n] = __builtin_amdgcn_mfma_f32_16x16x32_bf16(a[m], b[n], acc[m][n], 0, 0, 0);
  }

  const int cr = (lane >> 4) * 4;
  const int ccx = lane & 15;
#pragma unroll
  for (int m = 0; m < 4; ++m)
#pragma unroll
    for (int r = 0; r < 4; ++r) {
      const int gl = rb * 128 + wr * 64 + m * 16 + cr + r;
      if (gl >= cnt) continue;
      const int tok = list[gl];
      const float g = combine[(size_t)tok * 4 + e];
      float* orow = out + (size_t)tok * N;
#pragma unroll
      for (int n = 0; n < 4; ++n) {
        const int gc = bcol + wc * 64 + n * 16 + ccx;
        orow[gc] += g * (acc[m][n][r] + bias[gc]);
      }
    }
}

// ---------------------------------------------------------------------------
extern "C" void kernel_launch(void* const* d_in, const int* in_sizes, int n_in,
                              void* d_out, int out_size, void* d_ws,
                              size_t ws_size, hipStream_t stream) {
  const float* x = (const float*)d_in[0];
  const float* rW1 = (const float*)d_in[1];
  const float* rb1 = (const float*)d_in[2];
  const float* rW2 = (const float*)d_in[3];
  const float* rb2 = (const float*)d_in[4];
  const float* We1 = (const float*)d_in[5];
  const float* be1 = (const float*)d_in[6];
  const float* We2 = (const float*)d_in[7];
  const float* be2 = (const float*)d_in[8];
  float* out = (float*)d_out;

  const int T = 8192, D = 1024, D2 = 2048, H = 4096, E = 4;

  char* ws = (char*)d_ws;
  size_t off = 0;
  auto alloc = [&](size_t bytes) {
    char* p = ws + off;
    off = (off + bytes + 255) & ~(size_t)255;
    return p;
  };
  u16* x_hi = (u16*)alloc((size_t)T * D * 2);          // 16 MB
  u16* x_lo = (u16*)alloc((size_t)T * D * 2);          // 16 MB
  u16* rW1T_hi = (u16*)alloc((size_t)D2 * D * 2);      // 4 MB
  u16* rW1T_lo = (u16*)alloc((size_t)D2 * D * 2);      // 4 MB
  u16* h = (u16*)alloc((size_t)T * H * 2);             // 64 MB
  float* parts = (float*)h;  // [16][8192][4] = 2 MB; dead before h written
  float* combine = (float*)alloc((size_t)T * 4 * 4);
  int* cnt = (int*)alloc(4 * 4);
  int* list = (int*)alloc((size_t)4 * 8192 * 4);
  u16* We1T = (u16*)alloc((size_t)H * D * 2);          // 8 MB
  u16* We2T = (u16*)alloc((size_t)D * H * 2);          // 8 MB
  (void)ws_size;  // ~116 MB required

  hipMemsetAsync(cnt, 0, 16, stream);
  hipMemsetAsync(out, 0, (size_t)T * D * 4, stream);

  dim3 tb(32, 8);

  // 1. x -> bf16 hi/lo
  convert_split_kernel<<<2048, 256, 0, stream>>>(x, x_hi, x_lo, T * D / 4);
  // 2. rW1 [1024][2048] -> rW1T [2048][1024] hi/lo
  transpose_split_kernel<<<dim3(D2 / 32, D / 32), tb, 0, stream>>>(
      rW1, rW1T_hi, rW1T_lo, D, D2);
  // 3. fused router GEMM1 + partial-logits epilogue (rh never materialized)
  gemm3_router_kernel<<<dim3(16, 64), 256, 0, stream>>>(
      x_hi, x_lo, rW1T_hi, rW1T_lo, D, rb1, rW2, parts);
  // 4. router head: deterministic parts reduce + softmax + top2 + lists
  topk_kernel<<<T / 256, 256, 0, stream>>>(parts, rb2, combine, cnt, list, T);
  // 5. sparse experts: fused transpose pair, gather-GEMM, scatter-GEMM
  for (int e = 0; e < E; ++e) {
    transpose_pair_kernel<<<8192, tb, 0, stream>>>(
        We1 + (size_t)e * D * H, We2 + (size_t)e * H * D, We1T, We2T);
    gemm_gather_kernel<<<dim3(32, 64), 256, 0, stream>>>(
        x_hi, We1T, list + e * 8192, cnt + e, D, be1 + (size_t)e * H, h, H);
    gemm_scatter_kernel<<<dim3(8, 64), 256, 0, stream>>>(
        h, We2T, list + e * 8192, cnt + e, H, e, be2 + (size_t)e * D, combine,
        out, D);
  }
}

// Round 6
// 833.526 us; speedup vs baseline: 1.8388x; 1.3124x over previous
//
#include <hip/hip_runtime.h>
#include <math.h>

// ---------------------------------------------------------------------------
// CoLT5 MoE layer, round 6 (base = round 5 minus the early-exit-hostile XCD
// swizzle on gather/scatter, plus 64x128 scatter tiles for 2x occupancy):
//  - gemm3 epilogue computes partial router logits (rh never hits HBM)
//  - gather-GEMM 128x128 (plain dispatch order: active blocks first)
//  - scatter-GEMM 64x128 tiles, grid (8,128): 512 active blocks, no atomics
// Shapes hard-coded: T=8192, D=1024, D2=2048, H=4096, E=4.  ws ~116 MB.
// ---------------------------------------------------------------------------

typedef short bf16x8 __attribute__((ext_vector_type(8)));
typedef float f32x4 __attribute__((ext_vector_type(4)));
typedef unsigned short u16;

__device__ __forceinline__ u16 f2bf(float f) {
  unsigned u = __float_as_uint(f);
  u += 0x7FFFu + ((u >> 16) & 1u);  // round-to-nearest-even
  return (u16)(u >> 16);
}
__device__ __forceinline__ float bf2f(u16 s) {
  return __uint_as_float(((unsigned)s) << 16);
}
__device__ __forceinline__ float gelu_f(float x) {
  return 0.5f * x * (1.0f + erff(x * 0.70710678118654752f));
}
__device__ __forceinline__ void gload_lds16(const void* g, void* l) {
  __builtin_amdgcn_global_load_lds(
      (const __attribute__((address_space(1))) void*)g,
      (__attribute__((address_space(3))) void*)l, 16, 0, 0);
}

// ---------------------------------------------------------------------------
// x (fp32) -> x_hi (bf16) + x_lo (bf16 residual); vectorized 8B stores
// ---------------------------------------------------------------------------
__global__ __launch_bounds__(256) void convert_split_kernel(
    const float* __restrict__ in, u16* __restrict__ hi, u16* __restrict__ lo,
    int n4) {
  int i = blockIdx.x * blockDim.x + threadIdx.x;
  int stride = gridDim.x * blockDim.x;
  for (; i < n4; i += stride) {
    float4 v = ((const float4*)in)[i];
    float f[4] = {v.x, v.y, v.z, v.w};
    ushort4 h4, l4;
    u16* hp = (u16*)&h4;
    u16* lp = (u16*)&l4;
#pragma unroll
    for (int u = 0; u < 4; ++u) {
      u16 h = f2bf(f[u]);
      hp[u] = h;
      lp[u] = f2bf(f[u] - bf2f(h));
    }
    ((ushort4*)hi)[i] = h4;
    ((ushort4*)lo)[i] = l4;
  }
}

// ---------------------------------------------------------------------------
// transpose fp32 [R][C] -> bf16 [C][R] hi + lo residual (for rW1)
// block (32,8); grid (C/32, R/32)
// ---------------------------------------------------------------------------
__global__ __launch_bounds__(256) void transpose_split_kernel(
    const float* __restrict__ in, u16* __restrict__ hi, u16* __restrict__ lo,
    int R, int C) {
  __shared__ float tile[32][33];
  const int c0 = blockIdx.x * 32, r0 = blockIdx.y * 32;
#pragma unroll
  for (int i = 0; i < 4; ++i) {
    int rr = threadIdx.y + i * 8;
    tile[rr][threadIdx.x] = in[(size_t)(r0 + rr) * C + c0 + threadIdx.x];
  }
  __syncthreads();
#pragma unroll
  for (int i = 0; i < 4; ++i) {
    int cc = threadIdx.y + i * 8;
    float v = tile[threadIdx.x][cc];
    u16 h = f2bf(v);
    size_t oidx = (size_t)(c0 + cc) * R + r0 + threadIdx.x;
    hi[oidx] = h;
    lo[oidx] = f2bf(v - bf2f(h));
  }
}

// ---------------------------------------------------------------------------
// fused expert-weight transpose: We1[e] [1024][4096] -> We1T [4096][1024] and
// We2[e] [4096][1024] -> We2T [1024][4096], both fp32->bf16.  grid 8192 flat.
// ---------------------------------------------------------------------------
__global__ __launch_bounds__(256) void transpose_pair_kernel(
    const float* __restrict__ We1e, const float* __restrict__ We2e,
    u16* __restrict__ We1T, u16* __restrict__ We2T) {
  __shared__ float tile[32][33];
  int b = blockIdx.x;
  const float* in;
  u16* out;
  int R, C, tx, ty;
  if (b < 4096) {
    in = We1e; out = We1T; R = 1024; C = 4096; tx = b & 127; ty = b >> 7;
  } else {
    b -= 4096;
    in = We2e; out = We2T; R = 4096; C = 1024; tx = b & 31; ty = b >> 5;
  }
  const int c0 = tx * 32, r0 = ty * 32;
#pragma unroll
  for (int i = 0; i < 4; ++i) {
    int rr = threadIdx.y + i * 8;
    tile[rr][threadIdx.x] = in[(size_t)(r0 + rr) * C + c0 + threadIdx.x];
  }
  __syncthreads();
#pragma unroll
  for (int i = 0; i < 4; ++i) {
    int cc = threadIdx.y + i * 8;
    out[(size_t)(c0 + cc) * R + r0 + threadIdx.x] = f2bf(tile[threadIdx.x][cc]);
  }
}

// ---------------------------------------------------------------------------
// Fused 3-product split-bf16 router GEMM + partial-logits epilogue:
//   z = gelu( x_hi*W_hi + x_lo*W_hi + x_hi*W_lo + rb1 )   (fp32, in-reg only)
//   parts[bx][row][e] = sum_{cols of this block} z * rW2[col][e]
// 128x128 tile, BK=32, 4 waves.  grid (16, 64), chunked XCD swizzle
// (full grid, no early exit -> swizzle is safe here).
// ---------------------------------------------------------------------------
__global__ __launch_bounds__(256) void gemm3_router_kernel(
    const u16* __restrict__ Ahi, const u16* __restrict__ Alo,
    const u16* __restrict__ Bhi, const u16* __restrict__ Blo, int K,
    const float* __restrict__ bias, const float* __restrict__ rW2,
    float* __restrict__ parts) {
  __shared__ alignas(16) u16 Sm[4 * 128 * 32];
  __shared__ float pls[2][128][4];
  const int tid = threadIdx.x;
  const int lane = tid & 63;
  const int w = tid >> 6;
  const int wr = w >> 1, wc = w & 1;

  // chunked bijective XCD swizzle (nwg = 16*64 = 1024, cpx = 128)
  const int flat = blockIdx.x + blockIdx.y * 16;
  const int swz = (flat & 7) * 128 + (flat >> 3);
  const int bxs = swz & 15;
  const int bys = swz >> 4;
  const int brow = bys * 128;
  const int bcol = bxs * 128;

  f32x4 acc[4][4] = {};
  char* S = (char*)Sm;
  const u16* srcs[4] = {Ahi + (size_t)brow * K, Alo + (size_t)brow * K,
                        Bhi + (size_t)bcol * K, Blo + (size_t)bcol * K};
  const int rA = lane & 15;
  const int kg2 = (lane >> 4) * 16;

  const int nk = K >> 5;
  for (int kt = 0; kt < nk; ++kt) {
    const int k0 = kt << 5;
    __syncthreads();
#pragma unroll
    for (int i = 0; i < 8; ++i) {
      int c = tid + 256 * i;
      int tile = c >> 9;
      int cc = c & 511;
      int row = cc >> 2;
      int kp = (cc & 3) << 3;
      gload_lds16(srcs[tile] + (size_t)row * K + (k0 + kp), S + c * 16);
    }
    __syncthreads();

    bf16x8 ah[4], al[4], bh[4], bl[4];
#pragma unroll
    for (int m = 0; m < 4; ++m) {
      int ro = (wr * 64 + m * 16 + rA) * 64 + kg2;
      ah[m] = *(const bf16x8*)(S + ro);
      al[m] = *(const bf16x8*)(S + 8192 + ro);
    }
#pragma unroll
    for (int n = 0; n < 4; ++n) {
      int ro = (wc * 64 + n * 16 + rA) * 64 + kg2;
      bh[n] = *(const bf16x8*)(S + 16384 + ro);
      bl[n] = *(const bf16x8*)(S + 24576 + ro);
    }
#pragma unroll
    for (int m = 0; m < 4; ++m)
#pragma unroll
      for (int n = 0; n < 4; ++n) {
        acc[m][n] = __builtin_amdgcn_mfma_f32_16x16x32_bf16(ah[m], bh[n], acc[m][n], 0, 0, 0);
        acc[m][n] = __builtin_amdgcn_mfma_f32_16x16x32_bf16(al[m], bh[n], acc[m][n], 0, 0, 0);
        acc[m][n] = __builtin_amdgcn_mfma_f32_16x16x32_bf16(ah[m], bl[n], acc[m][n], 0, 0, 0);
      }
  }

  // ---- epilogue: partial logits over this block's 128 cols ----
  const int cr = (lane >> 4) * 4;
  const int ccx = lane & 15;
  float4 w2v[4];
  float bv[4];
#pragma unroll
  for (int n = 0; n < 4; ++n) {
    const int gc = bcol + wc * 64 + n * 16 + ccx;
    w2v[n] = ((const float4*)rW2)[gc];
    bv[n] = bias[gc];
  }
#pragma unroll
  for (int m = 0; m < 4; ++m) {
    float pl[4][4];
#pragma unroll
    for (int r = 0; r < 4; ++r)
#pragma unroll
      for (int e = 0; e < 4; ++e) pl[r][e] = 0.f;
#pragma unroll
    for (int n = 0; n < 4; ++n)
#pragma unroll
      for (int r = 0; r < 4; ++r) {
        const float v = gelu_f(acc[m][n][r] + bv[n]);
        pl[r][0] += v * w2v[n].x;
        pl[r][1] += v * w2v[n].y;
        pl[r][2] += v * w2v[n].z;
        pl[r][3] += v * w2v[n].w;
      }
#pragma unroll
    for (int off = 8; off; off >>= 1)
#pragma unroll
      for (int r = 0; r < 4; ++r)
#pragma unroll
        for (int e = 0; e < 4; ++e) pl[r][e] += __shfl_xor(pl[r][e], off);
    if ((lane & 15) == 0) {
      const int row = wr * 64 + m * 16 + cr;
#pragma unroll
      for (int r = 0; r < 4; ++r)
#pragma unroll
        for (int e = 0; e < 4; ++e) pls[wc][row + r][e] = pl[r][e];
    }
  }
  __syncthreads();
  for (int i = tid; i < 512; i += 256) {
    const int row = i >> 2, e = i & 3;
    parts[((size_t)bxs * 8192 + brow + row) * 4 + e] =
        pls[0][row][e] + pls[1][row][e];
  }
}

// ---------------------------------------------------------------------------
// topk: logits = rb2 + sum_{s<16} parts[s][t][:] (fixed order, deterministic);
// softmax + top-2 -> combine[T][4]; per-expert token lists (wave ballot ->
// block LDS -> 1 atomic/expert/block).  One thread per token.
// ---------------------------------------------------------------------------
__global__ __launch_bounds__(256) void topk_kernel(
    const float* __restrict__ parts, const float* __restrict__ rb2,
    float* __restrict__ combine, int* __restrict__ cnt, int* __restrict__ list,
    int T) {
  const int t = blockIdx.x * 256 + threadIdx.x;
  const int w = threadIdx.x >> 6, lane = threadIdx.x & 63;
  __shared__ int wpre[4][4];
  __shared__ int gbase[4];

  float lg[4] = {rb2[0], rb2[1], rb2[2], rb2[3]};
#pragma unroll
  for (int s = 0; s < 16; ++s) {
    float4 pv = ((const float4*)parts)[(size_t)s * 8192 + t];
    lg[0] += pv.x;
    lg[1] += pv.y;
    lg[2] += pv.z;
    lg[3] += pv.w;
  }
  float mx = fmaxf(fmaxf(lg[0], lg[1]), fmaxf(lg[2], lg[3]));
  float p[4], sum = 0.f;
#pragma unroll
  for (int e = 0; e < 4; ++e) {
    p[e] = expf(lg[e] - mx);
    sum += p[e];
  }
  float inv = 1.0f / sum;
  int i1 = 0;
#pragma unroll
  for (int e = 1; e < 4; ++e)
    if (lg[e] > lg[i1]) i1 = e;  // strict > : lowest index wins ties (jax)
  int i2 = -1;
#pragma unroll
  for (int e = 0; e < 4; ++e)
    if (e != i1 && (i2 < 0 || lg[e] > lg[i2])) i2 = e;
  float4 cw = {0.f, 0.f, 0.f, 0.f};
  ((float*)&cw)[i1] = p[i1] * inv;
  ((float*)&cw)[i2] = p[i2] * inv;
  ((float4*)combine)[t] = cw;

  unsigned long long m[4];
#pragma unroll
  for (int e = 0; e < 4; ++e) m[e] = __ballot(i1 == e || i2 == e);
  if (lane == 0) {
#pragma unroll
    for (int e = 0; e < 4; ++e) wpre[w][e] = (int)__popcll(m[e]);
  }
  __syncthreads();
  if (threadIdx.x < 4) {
    const int e = threadIdx.x;
    int tot = 0;
#pragma unroll
    for (int ww = 0; ww < 4; ++ww) {
      int c = wpre[ww][e];
      wpre[ww][e] = tot;
      tot += c;
    }
    gbase[e] = atomicAdd(&cnt[e], tot);
  }
  __syncthreads();
  const unsigned long long lt = (1ull << lane) - 1ull;
  int p1 = gbase[i1] + wpre[w][i1] + (int)__popcll(m[i1] & lt);
  list[i1 * 8192 + p1] = t;
  int p2 = gbase[i2] + wpre[w][i2] + (int)__popcll(m[i2] & lt);
  list[i2 * 8192 + p2] = t;
}

// ---------------------------------------------------------------------------
// gather-GEMM (expert GEMM-A): rows = list[e] tokens of x_hi; Bt = We1T[e];
// h[packed] = bf16(gelu(acc + be1)).  grid (32, 64), plain order (active
// blocks dispatched first); early-exit on cnt.
// ---------------------------------------------------------------------------
__global__ __launch_bounds__(256) void gemm_gather_kernel(
    const u16* __restrict__ A, const u16* __restrict__ Bt,
    const int* __restrict__ list, const int* __restrict__ cnt_p, int K,
    const float* __restrict__ bias, u16* __restrict__ Cb, int N) {
  const int cnt = *cnt_p;
  const int rb = blockIdx.y;
  if (rb * 128 >= cnt) return;
  __shared__ alignas(16) u16 As[128 * 32];
  __shared__ alignas(16) u16 Bs[128 * 32];
  const int tid = threadIdx.x;
  const int lane = tid & 63;
  const int w = tid >> 6;
  const int wr = w >> 1, wc = w & 1;
  const int bcol = blockIdx.x * 128;

  // indirect A-row sources (per-lane global addresses; LDS dest stays linear)
  const int arow = tid >> 2;
  const int kp = (tid & 3) << 3;
  int g0 = rb * 128 + arow, g1 = g0 + 64;
  const int tok0 = (g0 < cnt) ? list[g0] : list[rb * 128];
  const int tok1 = (g1 < cnt) ? list[g1] : list[rb * 128];
  const u16* Asrc0 = A + (size_t)tok0 * K + kp;
  const u16* Asrc1 = A + (size_t)tok1 * K + kp;
  const u16* Bb = Bt + (size_t)bcol * K + (size_t)arow * K + kp;

  f32x4 acc[4][4] = {};
  char* AsB = (char*)As;
  char* BsB = (char*)Bs;
  const int rA = lane & 15;
  const int kg2 = (lane >> 4) * 16;

  const int nk = K >> 5;
  for (int kt = 0; kt < nk; ++kt) {
    const int k0 = kt << 5;
    __syncthreads();
    gload_lds16(Asrc0 + k0, AsB + tid * 16);
    gload_lds16(Asrc1 + k0, AsB + (tid + 256) * 16);
    gload_lds16(Bb + k0, BsB + tid * 16);
    gload_lds16(Bb + (size_t)64 * K + k0, BsB + (tid + 256) * 16);
    __syncthreads();

    bf16x8 a[4], b[4];
#pragma unroll
    for (int m = 0; m < 4; ++m)
      a[m] = *(const bf16x8*)(AsB + (wr * 64 + m * 16 + rA) * 64 + kg2);
#pragma unroll
    for (int n = 0; n < 4; ++n)
      b[n] = *(const bf16x8*)(BsB + (wc * 64 + n * 16 + rA) * 64 + kg2);
#pragma unroll
    for (int m = 0; m < 4; ++m)
#pragma unroll
      for (int n = 0; n < 4; ++n)
        acc[m][n] = __builtin_amdgcn_mfma_f32_16x16x32_bf16(a[m], b[n], acc[m][n], 0, 0, 0);
  }

  const int cr = (lane >> 4) * 4;
  const int ccx = lane & 15;
#pragma unroll
  for (int m = 0; m < 4; ++m)
#pragma unroll
    for (int n = 0; n < 4; ++n) {
      const int gc = bcol + wc * 64 + n * 16 + ccx;
      const float bv = bias[gc];
#pragma unroll
      for (int r = 0; r < 4; ++r) {
        const int gr = rb * 128 + wr * 64 + m * 16 + cr + r;
        Cb[(size_t)gr * N + gc] = f2bf(gelu_f(acc[m][n][r] + bv));
      }
    }
}

// ---------------------------------------------------------------------------
// scatter-GEMM (expert GEMM-B): A = packed h; out[tok] += g*(acc + be2).
// 64x128 tile (rows x cols), 4 waves (2Mx2N, 32x64 each), grid (8, 128):
// 2x the active blocks of a 128x128 tiling -> 2 blocks/CU.  Early-exit.
// Safe +=: one owner per (tok,col); experts serialized; out pre-zeroed.
// ---------------------------------------------------------------------------
__global__ __launch_bounds__(256) void gemm_scatter_kernel(
    const u16* __restrict__ A, const u16* __restrict__ Bt,
    const int* __restrict__ list, const int* __restrict__ cnt_p, int K, int e,
    const float* __restrict__ bias, const float* __restrict__ combine,
    float* __restrict__ out, int N) {
  const int cnt = *cnt_p;
  const int rb = blockIdx.y;
  if (rb * 64 >= cnt) return;
  __shared__ alignas(16) u16 As[64 * 32];
  __shared__ alignas(16) u16 Bs[128 * 32];
  const int tid = threadIdx.x;
  const int lane = tid & 63;
  const int w = tid >> 6;
  const int wr = w >> 1, wc = w & 1;
  const int bcol = blockIdx.x * 128;

  const u16* Ab = A + (size_t)rb * 64 * K;
  const u16* Bb = Bt + (size_t)bcol * K;
  f32x4 acc[2][4] = {};
  char* AsB = (char*)As;
  char* BsB = (char*)Bs;
  const int rA = lane & 15;
  const int kg2 = (lane >> 4) * 16;

  // staging: A tile 64x32 = 256 chunks (1/thread); B tile 128x32 = 512 (2/thr)
  const int arow = tid >> 2;        // 0..63
  const int akp = (tid & 3) << 3;

  const int nk = K >> 5;
  for (int kt = 0; kt < nk; ++kt) {
    const int k0 = kt << 5;
    __syncthreads();
    gload_lds16(Ab + (size_t)arow * K + (k0 + akp), AsB + tid * 16);
#pragma unroll
    for (int i = 0; i < 2; ++i) {
      int c = tid + 256 * i;
      int row = c >> 2;
      int kpp = (c & 3) << 3;
      gload_lds16(Bb + (size_t)row * K + (k0 + kpp), BsB + c * 16);
    }
    __syncthreads();

    bf16x8 a[2], b[4];
#pragma unroll
    for (int m = 0; m < 2; ++m)
      a[m] = *(const bf16x8*)(AsB + (wr * 32 + m * 16 + rA) * 64 + kg2);
#pragma unroll
    for (int n = 0; n < 4; ++n)
      b[n] = *(const bf16x8*)(BsB + (wc * 64 + n * 16 + rA) * 64 + kg2);
#pragma unroll
    for (int m = 0; m < 2; ++m)
#pragma unroll
      for (int n = 0; n < 4; ++n)
        acc[m][n] = __builtin_amdgcn_mfma_f32_16x16x32_bf16(a[m], b[n], acc[m][n], 0, 0, 0);
  }

  const int cr = (lane >> 4) * 4;
  const int ccx = lane & 15;
#pragma unroll
  for (int m = 0; m < 2; ++m)
#pragma unroll
    for (int r = 0; r < 4; ++r) {
      const int gl = rb * 64 + wr * 32 + m * 16 + cr + r;
      if (gl >= cnt) continue;
      const int tok = list[gl];
      const float g = combine[(size_t)tok * 4 + e];
      float* orow = out + (size_t)tok * N;
#pragma unroll
      for (int n = 0; n < 4; ++n) {
        const int gc = bcol + wc * 64 + n * 16 + ccx;
        orow[gc] += g * (acc[m][n][r] + bias[gc]);
      }
    }
}

// ---------------------------------------------------------------------------
extern "C" void kernel_launch(void* const* d_in, const int* in_sizes, int n_in,
                              void* d_out, int out_size, void* d_ws,
                              size_t ws_size, hipStream_t stream) {
  const float* x = (const float*)d_in[0];
  const float* rW1 = (const float*)d_in[1];
  const float* rb1 = (const float*)d_in[2];
  const float* rW2 = (const float*)d_in[3];
  const float* rb2 = (const float*)d_in[4];
  const float* We1 = (const float*)d_in[5];
  const float* be1 = (const float*)d_in[6];
  const float* We2 = (const float*)d_in[7];
  const float* be2 = (const float*)d_in[8];
  float* out = (float*)d_out;

  const int T = 8192, D = 1024, D2 = 2048, H = 4096, E = 4;

  char* ws = (char*)d_ws;
  size_t off = 0;
  auto alloc = [&](size_t bytes) {
    char* p = ws + off;
    off = (off + bytes + 255) & ~(size_t)255;
    return p;
  };
  u16* x_hi = (u16*)alloc((size_t)T * D * 2);          // 16 MB
  u16* x_lo = (u16*)alloc((size_t)T * D * 2);          // 16 MB
  u16* rW1T_hi = (u16*)alloc((size_t)D2 * D * 2);      // 4 MB
  u16* rW1T_lo = (u16*)alloc((size_t)D2 * D * 2);      // 4 MB
  u16* h = (u16*)alloc((size_t)T * H * 2);             // 64 MB
  float* parts = (float*)h;  // [16][8192][4] = 2 MB; dead before h written
  float* combine = (float*)alloc((size_t)T * 4 * 4);
  int* cnt = (int*)alloc(4 * 4);
  int* list = (int*)alloc((size_t)4 * 8192 * 4);
  u16* We1T = (u16*)alloc((size_t)H * D * 2);          // 8 MB
  u16* We2T = (u16*)alloc((size_t)D * H * 2);          // 8 MB
  (void)ws_size;  // ~116 MB required

  hipMemsetAsync(cnt, 0, 16, stream);
  hipMemsetAsync(out, 0, (size_t)T * D * 4, stream);

  dim3 tb(32, 8);

  // 1. x -> bf16 hi/lo
  convert_split_kernel<<<2048, 256, 0, stream>>>(x, x_hi, x_lo, T * D / 4);
  // 2. rW1 [1024][2048] -> rW1T [2048][1024] hi/lo
  transpose_split_kernel<<<dim3(D2 / 32, D / 32), tb, 0, stream>>>(
      rW1, rW1T_hi, rW1T_lo, D, D2);
  // 3. fused router GEMM1 + partial-logits epilogue (rh never materialized)
  gemm3_router_kernel<<<dim3(16, 64), 256, 0, stream>>>(
      x_hi, x_lo, rW1T_hi, rW1T_lo, D, rb1, rW2, parts);
  // 4. router head: deterministic parts reduce + softmax + top2 + lists
  topk_kernel<<<T / 256, 256, 0, stream>>>(parts, rb2, combine, cnt, list, T);
  // 5. sparse experts: fused transpose pair, gather-GEMM, scatter-GEMM
  for (int e = 0; e < E; ++e) {
    transpose_pair_kernel<<<8192, tb, 0, stream>>>(
        We1 + (size_t)e * D * H, We2 + (size_t)e * H * D, We1T, We2T);
    gemm_gather_kernel<<<dim3(32, 64), 256, 0, stream>>>(
        x_hi, We1T, list + e * 8192, cnt + e, D, be1 + (size_t)e * H, h, H);
    gemm_scatter_kernel<<<dim3(8, 128), 256, 0, stream>>>(
        h, We2T, list + e * 8192, cnt + e, H, e, be2 + (size_t)e * D, combine,
        out, D);
  }
}

// Round 7
// 821.545 us; speedup vs baseline: 1.8656x; 1.0146x over previous
//
#include <hip/hip_runtime.h>
#include <math.h>

// ---------------------------------------------------------------------------
// CoLT5 MoE layer, round 7 (base = round 6, 833us):
//  - scatter-GEMM: 128x128 tiles + split-K (z=2) + atomicAdd epilogue
//    (was 64x128: 8 MFMA/K-step/wave -> 16, 2x occupancy of active blocks)
//  - expert-path GELU via tanh/exp (~12 VALU) instead of erff (~25+);
//    router keeps exact erff (top-2 ordering is the precision hazard)
// Shapes hard-coded: T=8192, D=1024, D2=2048, H=4096, E=4.  ws ~116 MB.
// ---------------------------------------------------------------------------

typedef short bf16x8 __attribute__((ext_vector_type(8)));
typedef float f32x4 __attribute__((ext_vector_type(4)));
typedef unsigned short u16;

__device__ __forceinline__ u16 f2bf(float f) {
  unsigned u = __float_as_uint(f);
  u += 0x7FFFu + ((u >> 16) & 1u);  // round-to-nearest-even
  return (u16)(u >> 16);
}
__device__ __forceinline__ float bf2f(u16 s) {
  return __uint_as_float(((unsigned)s) << 16);
}
// exact gelu (router path: logit precision decides top-2 ordering)
__device__ __forceinline__ float gelu_f(float x) {
  return 0.5f * x * (1.0f + erff(x * 0.70710678118654752f));
}
// fast gelu (expert path: h is bf16-quantized; |err|<=3e-3 << 0.119 threshold)
__device__ __forceinline__ float gelu_fast(float x) {
  float y = 1.5957691216057308f * (x + 0.044715f * x * x * x);  // 2*0.79788456*(..)
  float e = __expf(y);                                           // e^(2t)
  float t = 1.0f - 2.0f * __builtin_amdgcn_rcpf(e + 1.0f);       // tanh(t)
  return 0.5f * x * (1.0f + t);
}
__device__ __forceinline__ void gload_lds16(const void* g, void* l) {
  __builtin_amdgcn_global_load_lds(
      (const __attribute__((address_space(1))) void*)g,
      (__attribute__((address_space(3))) void*)l, 16, 0, 0);
}

// ---------------------------------------------------------------------------
// x (fp32) -> x_hi (bf16) + x_lo (bf16 residual); vectorized 8B stores
// ---------------------------------------------------------------------------
__global__ __launch_bounds__(256) void convert_split_kernel(
    const float* __restrict__ in, u16* __restrict__ hi, u16* __restrict__ lo,
    int n4) {
  int i = blockIdx.x * blockDim.x + threadIdx.x;
  int stride = gridDim.x * blockDim.x;
  for (; i < n4; i += stride) {
    float4 v = ((const float4*)in)[i];
    float f[4] = {v.x, v.y, v.z, v.w};
    ushort4 h4, l4;
    u16* hp = (u16*)&h4;
    u16* lp = (u16*)&l4;
#pragma unroll
    for (int u = 0; u < 4; ++u) {
      u16 h = f2bf(f[u]);
      hp[u] = h;
      lp[u] = f2bf(f[u] - bf2f(h));
    }
    ((ushort4*)hi)[i] = h4;
    ((ushort4*)lo)[i] = l4;
  }
}

// ---------------------------------------------------------------------------
// transpose fp32 [R][C] -> bf16 [C][R] hi + lo residual (for rW1)
// block (32,8); grid (C/32, R/32)
// ---------------------------------------------------------------------------
__global__ __launch_bounds__(256) void transpose_split_kernel(
    const float* __restrict__ in, u16* __restrict__ hi, u16* __restrict__ lo,
    int R, int C) {
  __shared__ float tile[32][33];
  const int c0 = blockIdx.x * 32, r0 = blockIdx.y * 32;
#pragma unroll
  for (int i = 0; i < 4; ++i) {
    int rr = threadIdx.y + i * 8;
    tile[rr][threadIdx.x] = in[(size_t)(r0 + rr) * C + c0 + threadIdx.x];
  }
  __syncthreads();
#pragma unroll
  for (int i = 0; i < 4; ++i) {
    int cc = threadIdx.y + i * 8;
    float v = tile[threadIdx.x][cc];
    u16 h = f2bf(v);
    size_t oidx = (size_t)(c0 + cc) * R + r0 + threadIdx.x;
    hi[oidx] = h;
    lo[oidx] = f2bf(v - bf2f(h));
  }
}

// ---------------------------------------------------------------------------
// fused expert-weight transpose: We1[e] [1024][4096] -> We1T [4096][1024] and
// We2[e] [4096][1024] -> We2T [1024][4096], both fp32->bf16.  grid 8192 flat.
// ---------------------------------------------------------------------------
__global__ __launch_bounds__(256) void transpose_pair_kernel(
    const float* __restrict__ We1e, const float* __restrict__ We2e,
    u16* __restrict__ We1T, u16* __restrict__ We2T) {
  __shared__ float tile[32][33];
  int b = blockIdx.x;
  const float* in;
  u16* out;
  int R, C, tx, ty;
  if (b < 4096) {
    in = We1e; out = We1T; R = 1024; C = 4096; tx = b & 127; ty = b >> 7;
  } else {
    b -= 4096;
    in = We2e; out = We2T; R = 4096; C = 1024; tx = b & 31; ty = b >> 5;
  }
  const int c0 = tx * 32, r0 = ty * 32;
#pragma unroll
  for (int i = 0; i < 4; ++i) {
    int rr = threadIdx.y + i * 8;
    tile[rr][threadIdx.x] = in[(size_t)(r0 + rr) * C + c0 + threadIdx.x];
  }
  __syncthreads();
#pragma unroll
  for (int i = 0; i < 4; ++i) {
    int cc = threadIdx.y + i * 8;
    out[(size_t)(c0 + cc) * R + r0 + threadIdx.x] = f2bf(tile[threadIdx.x][cc]);
  }
}

// ---------------------------------------------------------------------------
// Fused 3-product split-bf16 router GEMM + partial-logits epilogue:
//   z = gelu( x_hi*W_hi + x_lo*W_hi + x_hi*W_lo + rb1 )   (fp32, in-reg only)
//   parts[bx][row][e] = sum_{cols of this block} z * rW2[col][e]
// 128x128 tile, BK=32, 4 waves.  grid (16, 64), chunked XCD swizzle
// (full grid, no early exit -> swizzle is safe here).
// ---------------------------------------------------------------------------
__global__ __launch_bounds__(256) void gemm3_router_kernel(
    const u16* __restrict__ Ahi, const u16* __restrict__ Alo,
    const u16* __restrict__ Bhi, const u16* __restrict__ Blo, int K,
    const float* __restrict__ bias, const float* __restrict__ rW2,
    float* __restrict__ parts) {
  __shared__ alignas(16) u16 Sm[4 * 128 * 32];
  __shared__ float pls[2][128][4];
  const int tid = threadIdx.x;
  const int lane = tid & 63;
  const int w = tid >> 6;
  const int wr = w >> 1, wc = w & 1;

  // chunked bijective XCD swizzle (nwg = 16*64 = 1024, cpx = 128)
  const int flat = blockIdx.x + blockIdx.y * 16;
  const int swz = (flat & 7) * 128 + (flat >> 3);
  const int bxs = swz & 15;
  const int bys = swz >> 4;
  const int brow = bys * 128;
  const int bcol = bxs * 128;

  f32x4 acc[4][4] = {};
  char* S = (char*)Sm;
  const u16* srcs[4] = {Ahi + (size_t)brow * K, Alo + (size_t)brow * K,
                        Bhi + (size_t)bcol * K, Blo + (size_t)bcol * K};
  const int rA = lane & 15;
  const int kg2 = (lane >> 4) * 16;

  const int nk = K >> 5;
  for (int kt = 0; kt < nk; ++kt) {
    const int k0 = kt << 5;
    __syncthreads();
#pragma unroll
    for (int i = 0; i < 8; ++i) {
      int c = tid + 256 * i;
      int tile = c >> 9;
      int cc = c & 511;
      int row = cc >> 2;
      int kp = (cc & 3) << 3;
      gload_lds16(srcs[tile] + (size_t)row * K + (k0 + kp), S + c * 16);
    }
    __syncthreads();

    bf16x8 ah[4], al[4], bh[4], bl[4];
#pragma unroll
    for (int m = 0; m < 4; ++m) {
      int ro = (wr * 64 + m * 16 + rA) * 64 + kg2;
      ah[m] = *(const bf16x8*)(S + ro);
      al[m] = *(const bf16x8*)(S + 8192 + ro);
    }
#pragma unroll
    for (int n = 0; n < 4; ++n) {
      int ro = (wc * 64 + n * 16 + rA) * 64 + kg2;
      bh[n] = *(const bf16x8*)(S + 16384 + ro);
      bl[n] = *(const bf16x8*)(S + 24576 + ro);
    }
#pragma unroll
    for (int m = 0; m < 4; ++m)
#pragma unroll
      for (int n = 0; n < 4; ++n) {
        acc[m][n] = __builtin_amdgcn_mfma_f32_16x16x32_bf16(ah[m], bh[n], acc[m][n], 0, 0, 0);
        acc[m][n] = __builtin_amdgcn_mfma_f32_16x16x32_bf16(al[m], bh[n], acc[m][n], 0, 0, 0);
        acc[m][n] = __builtin_amdgcn_mfma_f32_16x16x32_bf16(ah[m], bl[n], acc[m][n], 0, 0, 0);
      }
  }

  // ---- epilogue: partial logits over this block's 128 cols ----
  const int cr = (lane >> 4) * 4;
  const int ccx = lane & 15;
  float4 w2v[4];
  float bv[4];
#pragma unroll
  for (int n = 0; n < 4; ++n) {
    const int gc = bcol + wc * 64 + n * 16 + ccx;
    w2v[n] = ((const float4*)rW2)[gc];
    bv[n] = bias[gc];
  }
#pragma unroll
  for (int m = 0; m < 4; ++m) {
    float pl[4][4];
#pragma unroll
    for (int r = 0; r < 4; ++r)
#pragma unroll
      for (int e = 0; e < 4; ++e) pl[r][e] = 0.f;
#pragma unroll
    for (int n = 0; n < 4; ++n)
#pragma unroll
      for (int r = 0; r < 4; ++r) {
        const float v = gelu_f(acc[m][n][r] + bv[n]);
        pl[r][0] += v * w2v[n].x;
        pl[r][1] += v * w2v[n].y;
        pl[r][2] += v * w2v[n].z;
        pl[r][3] += v * w2v[n].w;
      }
#pragma unroll
    for (int off = 8; off; off >>= 1)
#pragma unroll
      for (int r = 0; r < 4; ++r)
#pragma unroll
        for (int e = 0; e < 4; ++e) pl[r][e] += __shfl_xor(pl[r][e], off);
    if ((lane & 15) == 0) {
      const int row = wr * 64 + m * 16 + cr;
#pragma unroll
      for (int r = 0; r < 4; ++r)
#pragma unroll
        for (int e = 0; e < 4; ++e) pls[wc][row + r][e] = pl[r][e];
    }
  }
  __syncthreads();
  for (int i = tid; i < 512; i += 256) {
    const int row = i >> 2, e = i & 3;
    parts[((size_t)bxs * 8192 + brow + row) * 4 + e] =
        pls[0][row][e] + pls[1][row][e];
  }
}

// ---------------------------------------------------------------------------
// topk: logits = rb2 + sum_{s<16} parts[s][t][:] (fixed order, deterministic);
// softmax + top-2 -> combine[T][4]; per-expert token lists (wave ballot ->
// block LDS -> 1 atomic/expert/block).  One thread per token.
// ---------------------------------------------------------------------------
__global__ __launch_bounds__(256) void topk_kernel(
    const float* __restrict__ parts, const float* __restrict__ rb2,
    float* __restrict__ combine, int* __restrict__ cnt, int* __restrict__ list,
    int T) {
  const int t = blockIdx.x * 256 + threadIdx.x;
  const int w = threadIdx.x >> 6, lane = threadIdx.x & 63;
  __shared__ int wpre[4][4];
  __shared__ int gbase[4];

  float lg[4] = {rb2[0], rb2[1], rb2[2], rb2[3]};
#pragma unroll
  for (int s = 0; s < 16; ++s) {
    float4 pv = ((const float4*)parts)[(size_t)s * 8192 + t];
    lg[0] += pv.x;
    lg[1] += pv.y;
    lg[2] += pv.z;
    lg[3] += pv.w;
  }
  float mx = fmaxf(fmaxf(lg[0], lg[1]), fmaxf(lg[2], lg[3]));
  float p[4], sum = 0.f;
#pragma unroll
  for (int e = 0; e < 4; ++e) {
    p[e] = expf(lg[e] - mx);
    sum += p[e];
  }
  float inv = 1.0f / sum;
  int i1 = 0;
#pragma unroll
  for (int e = 1; e < 4; ++e)
    if (lg[e] > lg[i1]) i1 = e;  // strict > : lowest index wins ties (jax)
  int i2 = -1;
#pragma unroll
  for (int e = 0; e < 4; ++e)
    if (e != i1 && (i2 < 0 || lg[e] > lg[i2])) i2 = e;
  float4 cw = {0.f, 0.f, 0.f, 0.f};
  ((float*)&cw)[i1] = p[i1] * inv;
  ((float*)&cw)[i2] = p[i2] * inv;
  ((float4*)combine)[t] = cw;

  unsigned long long m[4];
#pragma unroll
  for (int e = 0; e < 4; ++e) m[e] = __ballot(i1 == e || i2 == e);
  if (lane == 0) {
#pragma unroll
    for (int e = 0; e < 4; ++e) wpre[w][e] = (int)__popcll(m[e]);
  }
  __syncthreads();
  if (threadIdx.x < 4) {
    const int e = threadIdx.x;
    int tot = 0;
#pragma unroll
    for (int ww = 0; ww < 4; ++ww) {
      int c = wpre[ww][e];
      wpre[ww][e] = tot;
      tot += c;
    }
    gbase[e] = atomicAdd(&cnt[e], tot);
  }
  __syncthreads();
  const unsigned long long lt = (1ull << lane) - 1ull;
  int p1 = gbase[i1] + wpre[w][i1] + (int)__popcll(m[i1] & lt);
  list[i1 * 8192 + p1] = t;
  int p2 = gbase[i2] + wpre[w][i2] + (int)__popcll(m[i2] & lt);
  list[i2 * 8192 + p2] = t;
}

// ---------------------------------------------------------------------------
// gather-GEMM (expert GEMM-A): rows = list[e] tokens of x_hi; Bt = We1T[e];
// h[packed] = bf16(gelu_fast(acc + be1)).  grid (32, 64); early-exit on cnt.
// ---------------------------------------------------------------------------
__global__ __launch_bounds__(256) void gemm_gather_kernel(
    const u16* __restrict__ A, const u16* __restrict__ Bt,
    const int* __restrict__ list, const int* __restrict__ cnt_p, int K,
    const float* __restrict__ bias, u16* __restrict__ Cb, int N) {
  const int cnt = *cnt_p;
  const int rb = blockIdx.y;
  if (rb * 128 >= cnt) return;
  __shared__ alignas(16) u16 As[128 * 32];
  __shared__ alignas(16) u16 Bs[128 * 32];
  const int tid = threadIdx.x;
  const int lane = tid & 63;
  const int w = tid >> 6;
  const int wr = w >> 1, wc = w & 1;
  const int bcol = blockIdx.x * 128;

  // indirect A-row sources (per-lane global addresses; LDS dest stays linear)
  const int arow = tid >> 2;
  const int kp = (tid & 3) << 3;
  int g0 = rb * 128 + arow, g1 = g0 + 64;
  const int tok0 = (g0 < cnt) ? list[g0] : list[rb * 128];
  const int tok1 = (g1 < cnt) ? list[g1] : list[rb * 128];
  const u16* Asrc0 = A + (size_t)tok0 * K + kp;
  const u16* Asrc1 = A + (size_t)tok1 * K + kp;
  const u16* Bb = Bt + (size_t)bcol * K + (size_t)arow * K + kp;

  f32x4 acc[4][4] = {};
  char* AsB = (char*)As;
  char* BsB = (char*)Bs;
  const int rA = lane & 15;
  const int kg2 = (lane >> 4) * 16;

  const int nk = K >> 5;
  for (int kt = 0; kt < nk; ++kt) {
    const int k0 = kt << 5;
    __syncthreads();
    gload_lds16(Asrc0 + k0, AsB + tid * 16);
    gload_lds16(Asrc1 + k0, AsB + (tid + 256) * 16);
    gload_lds16(Bb + k0, BsB + tid * 16);
    gload_lds16(Bb + (size_t)64 * K + k0, BsB + (tid + 256) * 16);
    __syncthreads();

    bf16x8 a[4], b[4];
#pragma unroll
    for (int m = 0; m < 4; ++m)
      a[m] = *(const bf16x8*)(AsB + (wr * 64 + m * 16 + rA) * 64 + kg2);
#pragma unroll
    for (int n = 0; n < 4; ++n)
      b[n] = *(const bf16x8*)(BsB + (wc * 64 + n * 16 + rA) * 64 + kg2);
#pragma unroll
    for (int m = 0; m < 4; ++m)
#pragma unroll
      for (int n = 0; n < 4; ++n)
        acc[m][n] = __builtin_amdgcn_mfma_f32_16x16x32_bf16(a[m], b[n], acc[m][n], 0, 0, 0);
  }

  const int cr = (lane >> 4) * 4;
  const int ccx = lane & 15;
#pragma unroll
  for (int m = 0; m < 4; ++m)
#pragma unroll
    for (int n = 0; n < 4; ++n) {
      const int gc = bcol + wc * 64 + n * 16 + ccx;
      const float bv = bias[gc];
#pragma unroll
      for (int r = 0; r < 4; ++r) {
        const int gr = rb * 128 + wr * 64 + m * 16 + cr + r;
        Cb[(size_t)gr * N + gc] = f2bf(gelu_fast(acc[m][n][r] + bv));
      }
    }
}

// ---------------------------------------------------------------------------
// scatter-GEMM (expert GEMM-B): A = packed h; out[tok] += g*(acc + be2@z0).
// 128x128 tile, split-K via blockIdx.z (2 halves of K=4096), grid (8, 64, 2);
// early-exit on cnt.  Epilogue: atomicAdd (2 in-dispatch contributions per
// element + experts serialized across dispatches; ~1ulp jitter << threshold).
// ---------------------------------------------------------------------------
__global__ __launch_bounds__(256) void gemm_scatter_kernel(
    const u16* __restrict__ A, const u16* __restrict__ Bt,
    const int* __restrict__ list, const int* __restrict__ cnt_p, int K, int e,
    const float* __restrict__ bias, const float* __restrict__ combine,
    float* __restrict__ out, int N) {
  const int cnt = *cnt_p;
  const int rb = blockIdx.y;
  if (rb * 128 >= cnt) return;
  __shared__ alignas(16) u16 As[128 * 32];
  __shared__ alignas(16) u16 Bs[128 * 32];
  const int tid = threadIdx.x;
  const int lane = tid & 63;
  const int w = tid >> 6;
  const int wr = w >> 1, wc = w & 1;
  const int bcol = blockIdx.x * 128;
  const int koff = (int)blockIdx.z * (K >> 1);  // z in {0,1}: K halves

  const u16* Ab = A + (size_t)rb * 128 * K + koff;
  const u16* Bb = Bt + (size_t)bcol * K + koff;
  f32x4 acc[4][4] = {};
  char* AsB = (char*)As;
  char* BsB = (char*)Bs;
  const int rA = lane & 15;
  const int kg2 = (lane >> 4) * 16;

  const int nk = K >> 6;  // (K/2)/32 K-steps per z
  for (int kt = 0; kt < nk; ++kt) {
    const int k0 = kt << 5;
    __syncthreads();
#pragma unroll
    for (int i = 0; i < 2; ++i) {
      int c = tid + 256 * i;
      int row = c >> 2;
      int kpp = (c & 3) << 3;
      gload_lds16(Ab + (size_t)row * K + (k0 + kpp), AsB + c * 16);
      gload_lds16(Bb + (size_t)row * K + (k0 + kpp), BsB + c * 16);
    }
    __syncthreads();

    bf16x8 a[4], b[4];
#pragma unroll
    for (int m = 0; m < 4; ++m)
      a[m] = *(const bf16x8*)(AsB + (wr * 64 + m * 16 + rA) * 64 + kg2);
#pragma unroll
    for (int n = 0; n < 4; ++n)
      b[n] = *(const bf16x8*)(BsB + (wc * 64 + n * 16 + rA) * 64 + kg2);
#pragma unroll
    for (int m = 0; m < 4; ++m)
#pragma unroll
      for (int n = 0; n < 4; ++n)
        acc[m][n] = __builtin_amdgcn_mfma_f32_16x16x32_bf16(a[m], b[n], acc[m][n], 0, 0, 0);
  }

  const int cr = (lane >> 4) * 4;
  const int ccx = lane & 15;
  const bool addbias = (blockIdx.z == 0);
#pragma unroll
  for (int m = 0; m < 4; ++m)
#pragma unroll
    for (int r = 0; r < 4; ++r) {
      const int gl = rb * 128 + wr * 64 + m * 16 + cr + r;
      if (gl >= cnt) continue;
      const int tok = list[gl];
      const float g = combine[(size_t)tok * 4 + e];
      float* orow = out + (size_t)tok * N;
#pragma unroll
      for (int n = 0; n < 4; ++n) {
        const int gc = bcol + wc * 64 + n * 16 + ccx;
        float v = acc[m][n][r];
        if (addbias) v += bias[gc];
        atomicAdd(&orow[gc], g * v);
      }
    }
}

// ---------------------------------------------------------------------------
extern "C" void kernel_launch(void* const* d_in, const int* in_sizes, int n_in,
                              void* d_out, int out_size, void* d_ws,
                              size_t ws_size, hipStream_t stream) {
  const float* x = (const float*)d_in[0];
  const float* rW1 = (const float*)d_in[1];
  const float* rb1 = (const float*)d_in[2];
  const float* rW2 = (const float*)d_in[3];
  const float* rb2 = (const float*)d_in[4];
  const float* We1 = (const float*)d_in[5];
  const float* be1 = (const float*)d_in[6];
  const float* We2 = (const float*)d_in[7];
  const float* be2 = (const float*)d_in[8];
  float* out = (float*)d_out;

  const int T = 8192, D = 1024, D2 = 2048, H = 4096, E = 4;

  char* ws = (char*)d_ws;
  size_t off = 0;
  auto alloc = [&](size_t bytes) {
    char* p = ws + off;
    off = (off + bytes + 255) & ~(size_t)255;
    return p;
  };
  u16* x_hi = (u16*)alloc((size_t)T * D * 2);          // 16 MB
  u16* x_lo = (u16*)alloc((size_t)T * D * 2);          // 16 MB
  u16* rW1T_hi = (u16*)alloc((size_t)D2 * D * 2);      // 4 MB
  u16* rW1T_lo = (u16*)alloc((size_t)D2 * D * 2);      // 4 MB
  u16* h = (u16*)alloc((size_t)T * H * 2);             // 64 MB
  float* parts = (float*)h;  // [16][8192][4] = 2 MB; dead before h written
  float* combine = (float*)alloc((size_t)T * 4 * 4);
  int* cnt = (int*)alloc(4 * 4);
  int* list = (int*)alloc((size_t)4 * 8192 * 4);
  u16* We1T = (u16*)alloc((size_t)H * D * 2);          // 8 MB
  u16* We2T = (u16*)alloc((size_t)D * H * 2);          // 8 MB
  (void)ws_size;  // ~116 MB required

  hipMemsetAsync(cnt, 0, 16, stream);
  hipMemsetAsync(out, 0, (size_t)T * D * 4, stream);

  dim3 tb(32, 8);

  // 1. x -> bf16 hi/lo
  convert_split_kernel<<<2048, 256, 0, stream>>>(x, x_hi, x_lo, T * D / 4);
  // 2. rW1 [1024][2048] -> rW1T [2048][1024] hi/lo
  transpose_split_kernel<<<dim3(D2 / 32, D / 32), tb, 0, stream>>>(
      rW1, rW1T_hi, rW1T_lo, D, D2);
  // 3. fused router GEMM1 + partial-logits epilogue (rh never materialized)
  gemm3_router_kernel<<<dim3(16, 64), 256, 0, stream>>>(
      x_hi, x_lo, rW1T_hi, rW1T_lo, D, rb1, rW2, parts);
  // 4. router head: deterministic parts reduce + softmax + top2 + lists
  topk_kernel<<<T / 256, 256, 0, stream>>>(parts, rb2, combine, cnt, list, T);
  // 5. sparse experts: fused transpose pair, gather-GEMM, scatter-GEMM(splitK)
  for (int e = 0; e < E; ++e) {
    transpose_pair_kernel<<<8192, tb, 0, stream>>>(
        We1 + (size_t)e * D * H, We2 + (size_t)e * H * D, We1T, We2T);
    gemm_gather_kernel<<<dim3(32, 64), 256, 0, stream>>>(
        x_hi, We1T, list + e * 8192, cnt + e, D, be1 + (size_t)e * H, h, H);
    gemm_scatter_kernel<<<dim3(8, 64, 2), 256, 0, stream>>>(
        h, We2T, list + e * 8192, cnt + e, H, e, be2 + (size_t)e * D, combine,
        out, D);
  }
}